// Round 1
// baseline (358.777 us; speedup 1.0000x reference)
//
#include <hip/hip_runtime.h>

// Batched Kalman filter: B batches, N=8 state, M=4 measurement, fp32.
// One thread per batch, register-resident math (unchanged from R3).
// R4: all wide arrays (F,P,Q,H,R in; P_new,K out) are bounced through a
//     per-wave LDS buffer: cooperative coalesced float4 global accesses,
//     padded LDS layout (stride W+4 floats -> 16B-aligned b128, <=2-way
//     banks), wave-synchronous lgkmcnt fences (64-thread block = 1 wave,
//     no s_barrier -> prefetched vmcnt loads survive the fences).
// Outputs flat-concatenated: x_new[B*8], P_new[B*64], K[B*32].

#define EPS 1e-6f
#define SYMIDX(r, c) ((r) * ((r) + 1) / 2 + (c))

typedef float v4f __attribute__((ext_vector_type(4)));

// All prior ds_writes by this wave become visible to subsequent ds_reads by
// any lane of the wave. lgkmcnt only -> outstanding global loads unaffected.
__device__ __forceinline__ void wave_lds_fence() {
    asm volatile("s_waitcnt lgkmcnt(0)" ::: "memory");
    __builtin_amdgcn_wave_barrier();
}

// W = floats per batch (64/32/16). Wave covers 64 batches.
// Coalesced global load: lane j, iter i -> float4 chunk (i*64 + j).
template <int W>
__device__ __forceinline__ void stage_load(float4 (&tmp)[W / 4], const float* __restrict__ src,
                                           int lane, int maxchunk) {
    const float4* s4 = reinterpret_cast<const float4*>(src);
#pragma unroll
    for (int i = 0; i < W / 4; ++i) {
        int c = i * 64 + lane;
        if (c >= maxchunk) c = maxchunk - 1;  // tail-block clamp (data valid)
        tmp[i] = s4[c];
    }
}

// Scatter into padded per-batch LDS layout: batch b at word b*(W+4).
// stride W+4 keeps 16B alignment for b128 and spreads banks (<=2-way).
template <int W>
__device__ __forceinline__ void stage_write(const float4 (&tmp)[W / 4], float* buf, int lane) {
    constexpr int STR = W + 4;
#pragma unroll
    for (int i = 0; i < W / 4; ++i) {
        int c = i * 64 + lane;
        int bb = c / (W / 4);
        int e = c & (W / 4 - 1);
        *reinterpret_cast<float4*>(buf + bb * STR + e * 4) = tmp[i];
    }
}

__global__ __launch_bounds__(64) __attribute__((amdgpu_waves_per_eu(2, 4)))
void kf_kernel(const float* __restrict__ x_est,
               const float* __restrict__ P_est,
               const float* __restrict__ Fin,
               const float* __restrict__ Qin,
               const float* __restrict__ zin,
               const float* __restrict__ Hin,
               const float* __restrict__ Rin,
               float* __restrict__ out, int B) {
    const int lane = threadIdx.x;
    const int blockBase = blockIdx.x * 64;
    const int nb = (B - blockBase < 64) ? (B - blockBase) : 64;  // valid batches
    const int b = blockBase + lane;
    const size_t sb = (size_t)((b < B) ? b : (B - 1));
    const size_t wbase = (size_t)blockBase;

    __shared__ __align__(16) float buf[64 * 68];  // 17.4 KB, reused sequentially

    // Small per-lane loads, already well-coalesced: z 16B/batch, x 32B/batch.
    float4 zz = reinterpret_cast<const float4*>(zin)[sb];
    float4 xa = reinterpret_cast<const float4*>(x_est)[2 * sb];
    float4 xb = reinterpret_cast<const float4*>(x_est)[2 * sb + 1];

    // ---------------- stage F ----------------
    float4 tF[16];
    stage_load<64>(tF, Fin + wbase * 64, lane, nb * 16);
    stage_write<64>(tF, buf, lane);

    float4 tP[16];  // issue P loads; they fly across the fences below
    stage_load<64>(tP, P_est + wbase * 64, lane, nb * 16);

    wave_lds_fence();  // F visible
    float Fr[64];
    {
        const float* my = buf + lane * 68;
#pragma unroll
        for (int r = 0; r < 8; ++r) {
            float4 a = *reinterpret_cast<const float4*>(my + r * 8);
            float4 c4 = *reinterpret_cast<const float4*>(my + r * 8 + 4);
            Fr[r * 8 + 0] = a.x;  Fr[r * 8 + 1] = a.y;  Fr[r * 8 + 2] = a.z;  Fr[r * 8 + 3] = a.w;
            Fr[r * 8 + 4] = c4.x; Fr[r * 8 + 5] = c4.y; Fr[r * 8 + 6] = c4.z; Fr[r * 8 + 7] = c4.w;
        }
    }

    // x_pred = F x (overlaps P-load latency)
    float xp[8];
    {
        float x[8] = {xa.x, xa.y, xa.z, xa.w, xb.x, xb.y, xb.z, xb.w};
#pragma unroll
        for (int i = 0; i < 8; ++i) {
            float s = 0.f;
#pragma unroll
            for (int j = 0; j < 8; ++j) s += Fr[i * 8 + j] * x[j];
            xp[i] = s;
        }
    }

    wave_lds_fence();  // F reads done (WAR) before overwriting with P
    stage_write<64>(tP, buf, lane);

    float4 tQ[16];
    stage_load<64>(tQ, Qin + wbase * 64, lane, nb * 16);

    wave_lds_fence();  // P visible
    float Ps[36];      // lower triangle of symmetric P
    {
        const float* my = buf + lane * 68;
#pragma unroll
        for (int r = 0; r < 8; ++r) {
            float4 a = *reinterpret_cast<const float4*>(my + r * 8);
            float row[8];
            row[0] = a.x; row[1] = a.y; row[2] = a.z; row[3] = a.w;
            row[4] = row[5] = row[6] = row[7] = 0.f;
            if (r >= 4) {
                float4 c4 = *reinterpret_cast<const float4*>(my + r * 8 + 4);
                row[4] = c4.x; row[5] = c4.y; row[6] = c4.z; row[7] = c4.w;
            }
#pragma unroll
            for (int j = 0; j <= r; ++j) Ps[SYMIDX(r, j)] = row[j];
        }
    }

    wave_lds_fence();  // P reads done (WAR)
    stage_write<64>(tQ, buf, lane);

    float4 tH[8];
    stage_load<32>(tH, Hin + wbase * 32, lane, nb * 8);

    wave_lds_fence();  // Q visible
    // Pp(sym) = F P F^T + Q, fused row-wise; Q rows read from LDS in-loop
    float Pps[36];
    {
        const float* myq = buf + lane * 68;
#pragma unroll
        for (int i = 0; i < 8; ++i) {
            float Ti[8];
#pragma unroll
            for (int j = 0; j < 8; ++j) {
                float s = 0.f;
#pragma unroll
                for (int k = 0; k < 8; ++k) {
                    float pkj = (k >= j) ? Ps[SYMIDX(k, j)] : Ps[SYMIDX(j, k)];
                    s += Fr[i * 8 + k] * pkj;
                }
                Ti[j] = s;
            }
            float4 qa = *reinterpret_cast<const float4*>(myq + i * 8);
            float4 qb = qa;
            if (i >= 4) qb = *reinterpret_cast<const float4*>(myq + i * 8 + 4);
            float Qr[8] = {qa.x, qa.y, qa.z, qa.w, qb.x, qb.y, qb.z, qb.w};
#pragma unroll
            for (int j = 0; j <= i; ++j) {
                float s = Qr[j];
#pragma unroll
                for (int k = 0; k < 8; ++k) s += Ti[k] * Fr[j * 8 + k];
                Pps[SYMIDX(i, j)] = s;
            }
        }
    }
    // F, Ps dead here.

    wave_lds_fence();  // Q reads done (WAR)
    stage_write<32>(tH, buf, lane);

    float4 tR[4];
    stage_load<16>(tR, Rin + wbase * 16, lane, nb * 4);

    wave_lds_fence();  // H visible (stride-36 region)
    float Hm[32];
    {
        const float* my = buf + lane * 36;
#pragma unroll
        for (int r = 0; r < 4; ++r) {
            float4 a = *reinterpret_cast<const float4*>(my + r * 8);
            float4 c4 = *reinterpret_cast<const float4*>(my + r * 8 + 4);
            Hm[r * 8 + 0] = a.x;  Hm[r * 8 + 1] = a.y;  Hm[r * 8 + 2] = a.z;  Hm[r * 8 + 3] = a.w;
            Hm[r * 8 + 4] = c4.x; Hm[r * 8 + 5] = c4.y; Hm[r * 8 + 6] = c4.z; Hm[r * 8 + 7] = c4.w;
        }
    }

    wave_lds_fence();  // H reads done (WAR)
    stage_write<16>(tR, buf, lane);

    // HP = H * Pp (4x8) -- overlaps R-load latency
    float HP[32];
#pragma unroll
    for (int i = 0; i < 4; ++i)
#pragma unroll
        for (int j = 0; j < 8; ++j) {
            float s = 0.f;
#pragma unroll
            for (int k = 0; k < 8; ++k) {
                float pkj = (k >= j) ? Pps[SYMIDX(k, j)] : Pps[SYMIDX(j, k)];
                s += Hm[i * 8 + k] * pkj;
            }
            HP[i * 8 + j] = s;
        }

    // y = z - H x_pred
    float y[4];
    {
        float zv[4] = {zz.x, zz.y, zz.z, zz.w};
#pragma unroll
        for (int i = 0; i < 4; ++i) {
            float s = zv[i];
#pragma unroll
            for (int k = 0; k < 8; ++k) s -= Hm[i * 8 + k] * xp[k];
            y[i] = s;
        }
    }

    wave_lds_fence();  // R visible (stride-20 region)
    float S[16];
    {
        const float* my = buf + lane * 20;
#pragma unroll
        for (int i = 0; i < 4; ++i) {
            float4 r4 = *reinterpret_cast<const float4*>(my + i * 4);
            float Rr[4] = {r4.x, r4.y, r4.z, r4.w};
#pragma unroll
            for (int j = 0; j < 4; ++j) {
                float s = Rr[j];
#pragma unroll
                for (int k = 0; k < 8; ++k) s += HP[i * 8 + k] * Hm[j * 8 + k];
                if (i == j) s += EPS;
                S[i * 4 + j] = s;
            }
        }
    }

    // ---- Sinv via adjugate ----
    float inv[16];
    inv[0]  =  S[5]*S[10]*S[15] - S[5]*S[11]*S[14] - S[9]*S[6]*S[15] + S[9]*S[7]*S[14] + S[13]*S[6]*S[11] - S[13]*S[7]*S[10];
    inv[4]  = -S[4]*S[10]*S[15] + S[4]*S[11]*S[14] + S[8]*S[6]*S[15] - S[8]*S[7]*S[14] - S[12]*S[6]*S[11] + S[12]*S[7]*S[10];
    inv[8]  =  S[4]*S[9]*S[15]  - S[4]*S[11]*S[13] - S[8]*S[5]*S[15] + S[8]*S[7]*S[13] + S[12]*S[5]*S[11] - S[12]*S[7]*S[9];
    inv[12] = -S[4]*S[9]*S[14]  + S[4]*S[10]*S[13] + S[8]*S[5]*S[14] - S[8]*S[6]*S[13] - S[12]*S[5]*S[10] + S[12]*S[6]*S[9];
    inv[1]  = -S[1]*S[10]*S[15] + S[1]*S[11]*S[14] + S[9]*S[2]*S[15] - S[9]*S[3]*S[14] - S[13]*S[2]*S[11] + S[13]*S[3]*S[10];
    inv[5]  =  S[0]*S[10]*S[15] - S[0]*S[11]*S[14] - S[8]*S[2]*S[15] + S[8]*S[3]*S[14] + S[12]*S[2]*S[11] - S[12]*S[3]*S[10];
    inv[9]  = -S[0]*S[9]*S[15]  + S[0]*S[11]*S[13] + S[8]*S[1]*S[15] - S[8]*S[3]*S[13] - S[12]*S[1]*S[11] + S[12]*S[3]*S[9];
    inv[13] =  S[0]*S[9]*S[14]  - S[0]*S[10]*S[13] - S[8]*S[1]*S[14] + S[8]*S[2]*S[13] + S[12]*S[1]*S[10] - S[12]*S[2]*S[9];
    inv[2]  =  S[1]*S[6]*S[15]  - S[1]*S[7]*S[14]  - S[5]*S[2]*S[15] + S[5]*S[3]*S[14] + S[13]*S[2]*S[7]  - S[13]*S[3]*S[6];
    inv[6]  = -S[0]*S[6]*S[15]  + S[0]*S[7]*S[14]  + S[4]*S[2]*S[15] - S[4]*S[3]*S[14] - S[12]*S[2]*S[7]  + S[12]*S[3]*S[6];
    inv[10] =  S[0]*S[5]*S[15]  - S[0]*S[7]*S[13]  - S[4]*S[1]*S[15] + S[4]*S[3]*S[13] + S[12]*S[1]*S[7]  - S[12]*S[3]*S[5];
    inv[14] = -S[0]*S[5]*S[14]  + S[0]*S[6]*S[13]  + S[4]*S[1]*S[14] - S[4]*S[2]*S[13] - S[12]*S[1]*S[6]  + S[12]*S[2]*S[5];
    inv[3]  = -S[1]*S[6]*S[11]  + S[1]*S[7]*S[10]  + S[5]*S[2]*S[11] - S[5]*S[3]*S[10] - S[9]*S[2]*S[7]   + S[9]*S[3]*S[6];
    inv[7]  =  S[0]*S[6]*S[11]  - S[0]*S[7]*S[10]  - S[4]*S[2]*S[11] + S[4]*S[3]*S[10] + S[8]*S[2]*S[7]   - S[8]*S[3]*S[6];
    inv[11] = -S[0]*S[5]*S[11]  + S[0]*S[7]*S[9]   + S[4]*S[1]*S[11] - S[4]*S[3]*S[9]  - S[8]*S[1]*S[7]   + S[8]*S[3]*S[5];
    inv[15] =  S[0]*S[5]*S[10]  - S[0]*S[6]*S[9]   - S[4]*S[1]*S[10] + S[4]*S[2]*S[9]  + S[8]*S[1]*S[6]   - S[8]*S[2]*S[5];
    float det = S[0]*inv[0] + S[1]*inv[4] + S[2]*inv[8] + S[3]*inv[12];
    float rdet = 1.0f / det;
#pragma unroll
    for (int i = 0; i < 16; ++i) inv[i] *= rdet;
    // S dead here.

    // ---- K = (HP)^T * Sinv (Pp symmetric) ----
    float K[32];
#pragma unroll
    for (int i = 0; i < 8; ++i)
#pragma unroll
        for (int j = 0; j < 4; ++j) {
            float s = 0.f;
#pragma unroll
            for (int k = 0; k < 4; ++k) s += HP[k * 8 + i] * inv[k * 4 + j];
            K[i * 4 + j] = s;
        }
    // inv dead here.

    // ---- x_new = x_pred + K y; direct store (32B/batch, coalesced enough) ----
    if (b < B) {
        float xn[8];
#pragma unroll
        for (int i = 0; i < 8; ++i) {
            float s = xp[i];
#pragma unroll
            for (int k = 0; k < 4; ++k) s += K[i * 4 + k] * y[k];
            xn[i] = s;
        }
        v4f v0 = {xn[0], xn[1], xn[2], xn[3]};
        v4f v1 = {xn[4], xn[5], xn[6], xn[7]};
        v4f* xo = reinterpret_cast<v4f*>(out + (size_t)b * 8);
        __builtin_nontemporal_store(v0, xo);
        __builtin_nontemporal_store(v1, xo + 1);
    }

    // ---- P_new = Pp - K*HP -> LDS (stride 68) -> coalesced nt store ----
    wave_lds_fence();  // R LDS reads done (WAR) before reusing buf
    {
        float* my = buf + lane * 68;
#pragma unroll
        for (int i = 0; i < 8; ++i) {
            float r[8];
#pragma unroll
            for (int j = 0; j < 8; ++j) {
                float pij = (i >= j) ? Pps[SYMIDX(i, j)] : Pps[SYMIDX(j, i)];
                float s = pij;
#pragma unroll
                for (int k = 0; k < 4; ++k) s -= K[i * 4 + k] * HP[k * 8 + j];
                r[j] = s;
            }
            *reinterpret_cast<float4*>(my + i * 8)     = make_float4(r[0], r[1], r[2], r[3]);
            *reinterpret_cast<float4*>(my + i * 8 + 4) = make_float4(r[4], r[5], r[6], r[7]);
        }
    }
    wave_lds_fence();  // P_new visible
    {
        float* outP = out + (size_t)B * 8 + wbase * 64;
        const int maxc = nb * 16;
#pragma unroll
        for (int i = 0; i < 16; ++i) {
            int c = i * 64 + lane;
            if (c < maxc) {
                int bb = c >> 4, e = c & 15;
                v4f v = *reinterpret_cast<const v4f*>(buf + bb * 68 + e * 4);
                __builtin_nontemporal_store(v, reinterpret_cast<v4f*>(outP) + c);
            }
        }
    }

    // ---- K -> LDS (stride 36) -> coalesced nt store ----
    wave_lds_fence();  // P_new LDS reads done (WAR)
    {
        float* my = buf + lane * 36;
#pragma unroll
        for (int i = 0; i < 8; ++i)
            *reinterpret_cast<float4*>(my + i * 4) =
                make_float4(K[4 * i + 0], K[4 * i + 1], K[4 * i + 2], K[4 * i + 3]);
    }
    wave_lds_fence();  // K visible
    {
        float* outK = out + (size_t)B * 72 + wbase * 32;
        const int maxc = nb * 8;
#pragma unroll
        for (int i = 0; i < 8; ++i) {
            int c = i * 64 + lane;
            if (c < maxc) {
                int bb = c >> 3, e = c & 7;
                v4f v = *reinterpret_cast<const v4f*>(buf + bb * 36 + e * 4);
                __builtin_nontemporal_store(v, reinterpret_cast<v4f*>(outK) + c);
            }
        }
    }
}

extern "C" void kernel_launch(void* const* d_in, const int* in_sizes, int n_in,
                              void* d_out, int out_size, void* d_ws, size_t ws_size,
                              hipStream_t stream) {
    const float* x_est = (const float*)d_in[0];
    const float* P_est = (const float*)d_in[1];
    const float* F     = (const float*)d_in[2];
    const float* Q     = (const float*)d_in[3];
    const float* z     = (const float*)d_in[4];
    const float* H     = (const float*)d_in[5];
    const float* R     = (const float*)d_in[6];
    float* out = (float*)d_out;
    int B = in_sizes[0] / 8;
    int block = 64;
    int grid = (B + 63) / 64;
    kf_kernel<<<grid, block, 0, stream>>>(x_est, P_est, F, Q, z, H, R, out, B);
}

// Round 3
// 310.870 us; speedup vs baseline: 1.1541x; 1.1541x over previous
//
#include <hip/hip_runtime.h>

// Batched Kalman filter: B batches, N=8 state, M=4 meas, fp32.
// R6 = R5 (async cross-group pipeline) + two hardening fixes:
//  - F,P,Q staged via global_load_lds (48KB/group, LDS linear dest),
//    source pre-swizzled chunk e' = e ^ (b&7) so swizzled ds_read_b128
//    is bank-conflict-free (8 words/bank = b128 floor, verified mapping).
//  - Cross-group software pipeline: while computing group g, group g+1's
//    48 gl_lds stay in flight. ALL direct loads (H,R, next z/x) are issued
//    BEFORE the staging block, so the only post-staging vmem ops are the
//    26 unconditional float4 stores -> steady-state s_waitcnt vmcnt(26)
//    is robust: any extra compiler vmem op only makes it MORE conservative.
//  - global_load_lds pointers cast via uintptr_t (CK pattern): global AS1
//    same bits as generic; LDS AS3 = low 32 bits of generic.
//  - Outputs: plain cached stores (R4's nt-stores caused 2.4x write ampl).
// Outputs flat: x_new[B*8], P_new[B*64], K[B*32].

#define EPS 1e-6f
#define SYMIDX(r, c) ((r) * ((r) + 1) / 2 + (c))

__device__ __forceinline__ void gl_lds16(const float* g, float* l) {
    __builtin_amdgcn_global_load_lds(
        (const __attribute__((address_space(1))) void*)(uintptr_t)g,
        (__attribute__((address_space(3))) void*)(unsigned)(uintptr_t)l,
        16, 0, 0);
}

// Stage 64 batches x 64 floats into linear LDS via global_load_lds.
// LDS slot (b, e') holds global chunk e' ^ (b&7) of batch b: issue i covers
// slots i*64+lane with b = i*4 + lane/16, e' = lane&15. Global side: each
// issue reads a permutation of 4 full 256B batch rows -> 1KB coalesced.
__device__ __forceinline__ void stage64(const float* __restrict__ src, int gstart,
                                        float* ldsbase, int lane, int B) {
#pragma unroll
    for (int i = 0; i < 16; ++i) {
        int b = i * 4 + (lane >> 4);
        int e = lane & 15;
        int gb = gstart + b;
        if (gb > B - 1) gb = B - 1;
        gl_lds16(src + (size_t)gb * 64 + (size_t)((e ^ (b & 7)) * 4),
                 ldsbase + i * 256);
    }
}

__global__ __launch_bounds__(64) __attribute__((amdgpu_waves_per_eu(1)))
void kf_kernel(const float* __restrict__ x_est,
               const float* __restrict__ P_est,
               const float* __restrict__ Fin,
               const float* __restrict__ Qin,
               const float* __restrict__ zin,
               const float* __restrict__ Hin,
               const float* __restrict__ Rin,
               float* __restrict__ out, int B) {
    const int lane = threadIdx.x;
    const int ngroups = (B + 63) >> 6;
    int g = blockIdx.x;
    if (g >= ngroups) return;
    const int stride = gridDim.x;

    // F: floats [0,4096)  P: [4096,8192)  Q: [8192,12288)  = 48 KB
    __shared__ __align__(16) float lds[12288];

    // ---- prologue: stage group g, load its z/x, full drain ----
    stage64(Fin, g * 64, lds, lane, B);
    stage64(P_est, g * 64, lds + 4096, lane, B);
    stage64(Qin, g * 64, lds + 8192, lane, B);
    int bc = g * 64 + lane;
    if (bc > B - 1) bc = B - 1;
    float4 zz = reinterpret_cast<const float4*>(zin)[bc];
    float4 xa = reinterpret_cast<const float4*>(x_est)[2 * bc];
    float4 xb = reinterpret_cast<const float4*>(x_est)[2 * bc + 1];
    asm volatile("s_waitcnt vmcnt(0)" ::: "memory");

    while (true) {
        const int b0 = g * 64 + lane;
        const bool full = (g * 64 + 64 <= B);
        const int sw = lane & 7;
        const float4* L4 = reinterpret_cast<const float4*>(lds);
        const int gn = g + stride;
        const int gnc = (gn < ngroups) ? gn : 0;  // clamped prefetch target

        // ---- direct loads, ALL issued before the staging block ----
        // current-group H (8 loads), R (4); next-group z/x (3). 15 vmem.
        int b0c = (b0 > B - 1) ? B - 1 : b0;
        float Hm[32];
        {
            const float4* H4 = reinterpret_cast<const float4*>(Hin + (size_t)b0c * 32);
#pragma unroll
            for (int i = 0; i < 8; ++i) {
                float4 h = H4[i];
                Hm[4 * i + 0] = h.x; Hm[4 * i + 1] = h.y; Hm[4 * i + 2] = h.z; Hm[4 * i + 3] = h.w;
            }
        }
        const float4* Rp = reinterpret_cast<const float4*>(Rin + (size_t)b0c * 16);
        float4 r0 = Rp[0], r1 = Rp[1], r2 = Rp[2], r3 = Rp[3];
        int bcn = gnc * 64 + lane;
        if (bcn > B - 1) bcn = B - 1;
        float4 zzn = reinterpret_cast<const float4*>(zin)[bcn];
        float4 xan = reinterpret_cast<const float4*>(x_est)[2 * bcn];
        float4 xbn = reinterpret_cast<const float4*>(x_est)[2 * bcn + 1];

        // ---- LDS -> registers (swizzled, conflict-free ds_read_b128) ----
        float Fr[64];
#pragma unroll
        for (int r = 0; r < 8; ++r) {
            float4 a = L4[lane * 16 + ((2 * r) ^ sw)];
            float4 c = L4[lane * 16 + ((2 * r + 1) ^ sw)];
            Fr[r * 8 + 0] = a.x; Fr[r * 8 + 1] = a.y; Fr[r * 8 + 2] = a.z; Fr[r * 8 + 3] = a.w;
            Fr[r * 8 + 4] = c.x; Fr[r * 8 + 5] = c.y; Fr[r * 8 + 6] = c.z; Fr[r * 8 + 7] = c.w;
        }
        float Ps[36];
#pragma unroll
        for (int r = 0; r < 8; ++r) {
            float4 a = L4[1024 + lane * 16 + ((2 * r) ^ sw)];
            float rw[4] = {a.x, a.y, a.z, a.w};
            if (r < 4) {
#pragma unroll
                for (int j = 0; j < 4; ++j)
                    if (j <= r) Ps[SYMIDX(r, j)] = rw[j];
            } else {
                float4 c = L4[1024 + lane * 16 + ((2 * r + 1) ^ sw)];
                float rw2[4] = {c.x, c.y, c.z, c.w};
#pragma unroll
                for (int j = 0; j < 4; ++j) Ps[SYMIDX(r, j)] = rw[j];
#pragma unroll
                for (int j = 4; j < 8; ++j)
                    if (j <= r) Ps[SYMIDX(r, j)] = rw2[j - 4];
            }
        }
        float Qs[36];  // Q symmetric -> lower triangle only
#pragma unroll
        for (int r = 0; r < 8; ++r) {
            float4 a = L4[2048 + lane * 16 + ((2 * r) ^ sw)];
            float rw[4] = {a.x, a.y, a.z, a.w};
            if (r < 4) {
#pragma unroll
                for (int j = 0; j < 4; ++j)
                    if (j <= r) Qs[SYMIDX(r, j)] = rw[j];
            } else {
                float4 c = L4[2048 + lane * 16 + ((2 * r + 1) ^ sw)];
                float rw2[4] = {c.x, c.y, c.z, c.w};
#pragma unroll
                for (int j = 0; j < 4; ++j) Qs[SYMIDX(r, j)] = rw[j];
#pragma unroll
                for (int j = 4; j < 8; ++j)
                    if (j <= r) Qs[SYMIDX(r, j)] = rw2[j - 4];
            }
        }
        // WAR: all LDS reads complete before next group's gl_lds can land.
        asm volatile("s_waitcnt lgkmcnt(0)" ::: "memory");

        // ---- issue next group's staging (48 gl_lds, stay in flight) ----
        stage64(Fin, gnc * 64, lds, lane, B);
        stage64(P_est, gnc * 64, lds + 4096, lane, B);
        stage64(Qin, gnc * 64, lds + 8192, lane, B);
        // Compile barrier: no vmem crosses this point in either direction.
        // After here the ONLY vmem ops are the 26 float4 stores.
        asm volatile("" ::: "memory");

        // ---- x_pred = F x ----
        float xp[8];
        {
            float x[8] = {xa.x, xa.y, xa.z, xa.w, xb.x, xb.y, xb.z, xb.w};
#pragma unroll
            for (int i = 0; i < 8; ++i) {
                float s = 0.f;
#pragma unroll
                for (int j = 0; j < 8; ++j) s += Fr[i * 8 + j] * x[j];
                xp[i] = s;
            }
        }

        // ---- Pp(sym) = F P F^T + Q ----
        float Pps[36];
#pragma unroll
        for (int i = 0; i < 8; ++i) {
            float Ti[8];
#pragma unroll
            for (int j = 0; j < 8; ++j) {
                float s = 0.f;
#pragma unroll
                for (int k = 0; k < 8; ++k) {
                    float pkj = (k >= j) ? Ps[SYMIDX(k, j)] : Ps[SYMIDX(j, k)];
                    s += Fr[i * 8 + k] * pkj;
                }
                Ti[j] = s;
            }
#pragma unroll
            for (int j = 0; j <= i; ++j) {
                float s = Qs[SYMIDX(i, j)];
#pragma unroll
                for (int k = 0; k < 8; ++k) s += Ti[k] * Fr[j * 8 + k];
                Pps[SYMIDX(i, j)] = s;
            }
        }
        // Fr, Ps, Qs dead.

        // ---- HP = H * Pp ----
        float HP[32];
#pragma unroll
        for (int i = 0; i < 4; ++i)
#pragma unroll
            for (int j = 0; j < 8; ++j) {
                float s = 0.f;
#pragma unroll
                for (int k = 0; k < 8; ++k) {
                    float pkj = (k >= j) ? Pps[SYMIDX(k, j)] : Pps[SYMIDX(j, k)];
                    s += Hm[i * 8 + k] * pkj;
                }
                HP[i * 8 + j] = s;
            }

        // ---- y = z - H x_pred ----
        float y[4];
        {
            float zv[4] = {zz.x, zz.y, zz.z, zz.w};
#pragma unroll
            for (int i = 0; i < 4; ++i) {
                float s = zv[i];
#pragma unroll
                for (int k = 0; k < 8; ++k) s -= Hm[i * 8 + k] * xp[k];
                y[i] = s;
            }
        }

        // ---- S = HP H^T + R + eps I ----
        float S[16];
        {
            float Rr[16] = {r0.x, r0.y, r0.z, r0.w, r1.x, r1.y, r1.z, r1.w,
                            r2.x, r2.y, r2.z, r2.w, r3.x, r3.y, r3.z, r3.w};
#pragma unroll
            for (int i = 0; i < 4; ++i)
#pragma unroll
                for (int j = 0; j < 4; ++j) {
                    float s = Rr[i * 4 + j];
#pragma unroll
                    for (int k = 0; k < 8; ++k) s += HP[i * 8 + k] * Hm[j * 8 + k];
                    if (i == j) s += EPS;
                    S[i * 4 + j] = s;
                }
        }

        // ---- Sinv via adjugate ----
        float inv[16];
        inv[0]  =  S[5]*S[10]*S[15] - S[5]*S[11]*S[14] - S[9]*S[6]*S[15] + S[9]*S[7]*S[14] + S[13]*S[6]*S[11] - S[13]*S[7]*S[10];
        inv[4]  = -S[4]*S[10]*S[15] + S[4]*S[11]*S[14] + S[8]*S[6]*S[15] - S[8]*S[7]*S[14] - S[12]*S[6]*S[11] + S[12]*S[7]*S[10];
        inv[8]  =  S[4]*S[9]*S[15]  - S[4]*S[11]*S[13] - S[8]*S[5]*S[15] + S[8]*S[7]*S[13] + S[12]*S[5]*S[11] - S[12]*S[7]*S[9];
        inv[12] = -S[4]*S[9]*S[14]  + S[4]*S[10]*S[13] + S[8]*S[5]*S[14] - S[8]*S[6]*S[13] - S[12]*S[5]*S[10] + S[12]*S[6]*S[9];
        inv[1]  = -S[1]*S[10]*S[15] + S[1]*S[11]*S[14] + S[9]*S[2]*S[15] - S[9]*S[3]*S[14] - S[13]*S[2]*S[11] + S[13]*S[3]*S[10];
        inv[5]  =  S[0]*S[10]*S[15] - S[0]*S[11]*S[14] - S[8]*S[2]*S[15] + S[8]*S[3]*S[14] + S[12]*S[2]*S[11] - S[12]*S[3]*S[10];
        inv[9]  = -S[0]*S[9]*S[15]  + S[0]*S[11]*S[13] + S[8]*S[1]*S[15] - S[8]*S[3]*S[13] - S[12]*S[1]*S[11] + S[12]*S[3]*S[9];
        inv[13] =  S[0]*S[9]*S[14]  - S[0]*S[10]*S[13] - S[8]*S[1]*S[14] + S[8]*S[2]*S[13] + S[12]*S[1]*S[10] - S[12]*S[2]*S[9];
        inv[2]  =  S[1]*S[6]*S[15]  - S[1]*S[7]*S[14]  - S[5]*S[2]*S[15] + S[5]*S[3]*S[14] + S[13]*S[2]*S[7]  - S[13]*S[3]*S[6];
        inv[6]  = -S[0]*S[6]*S[15]  + S[0]*S[7]*S[14]  + S[4]*S[2]*S[15] - S[4]*S[3]*S[14] - S[12]*S[2]*S[7]  + S[12]*S[3]*S[6];
        inv[10] =  S[0]*S[5]*S[15]  - S[0]*S[7]*S[13]  - S[4]*S[1]*S[15] + S[4]*S[3]*S[13] + S[12]*S[1]*S[7]  - S[12]*S[3]*S[5];
        inv[14] = -S[0]*S[5]*S[14]  + S[0]*S[6]*S[13]  + S[4]*S[1]*S[14] - S[4]*S[2]*S[13] - S[12]*S[1]*S[6]  + S[12]*S[2]*S[5];
        inv[3]  = -S[1]*S[6]*S[11]  + S[1]*S[7]*S[10]  + S[5]*S[2]*S[11] - S[5]*S[3]*S[10] - S[9]*S[2]*S[7]   + S[9]*S[3]*S[6];
        inv[7]  =  S[0]*S[6]*S[11]  - S[0]*S[7]*S[10]  - S[4]*S[2]*S[11] + S[4]*S[3]*S[10] + S[8]*S[2]*S[7]   - S[8]*S[3]*S[6];
        inv[11] = -S[0]*S[5]*S[11]  + S[0]*S[7]*S[9]   + S[4]*S[1]*S[11] - S[4]*S[3]*S[9]  - S[8]*S[1]*S[7]   + S[8]*S[3]*S[5];
        inv[15] =  S[0]*S[5]*S[10]  - S[0]*S[6]*S[9]   - S[4]*S[1]*S[10] + S[4]*S[2]*S[9]  + S[8]*S[1]*S[6]   - S[8]*S[2]*S[5];
        float det = S[0]*inv[0] + S[1]*inv[4] + S[2]*inv[8] + S[3]*inv[12];
        float rdet = 1.0f / det;
#pragma unroll
        for (int i = 0; i < 16; ++i) inv[i] *= rdet;

        // ---- K = (HP)^T * Sinv (Pp symmetric) ----
        float K[32];
#pragma unroll
        for (int i = 0; i < 8; ++i)
#pragma unroll
            for (int j = 0; j < 4; ++j) {
                float s = 0.f;
#pragma unroll
                for (int k = 0; k < 4; ++k) s += HP[k * 8 + i] * inv[k * 4 + j];
                K[i * 4 + j] = s;
            }

        // ---- outputs: exactly 26 float4 cached stores ----
        auto doStores = [&]() {
            float4* xo = reinterpret_cast<float4*>(out + (size_t)b0 * 8);
            float xn[8];
#pragma unroll
            for (int i = 0; i < 8; ++i) {
                float s = xp[i];
#pragma unroll
                for (int k = 0; k < 4; ++k) s += K[i * 4 + k] * y[k];
                xn[i] = s;
            }
            xo[0] = make_float4(xn[0], xn[1], xn[2], xn[3]);
            xo[1] = make_float4(xn[4], xn[5], xn[6], xn[7]);

            float4* po = reinterpret_cast<float4*>(out + (size_t)B * 8 + (size_t)b0 * 64);
#pragma unroll
            for (int i = 0; i < 8; ++i) {
                float r[8];
#pragma unroll
                for (int j = 0; j < 8; ++j) {
                    float pij = (i >= j) ? Pps[SYMIDX(i, j)] : Pps[SYMIDX(j, i)];
                    float s = pij;
#pragma unroll
                    for (int k = 0; k < 4; ++k) s -= K[i * 4 + k] * HP[k * 8 + j];
                    r[j] = s;
                }
                po[2 * i + 0] = make_float4(r[0], r[1], r[2], r[3]);
                po[2 * i + 1] = make_float4(r[4], r[5], r[6], r[7]);
            }

            float4* ko = reinterpret_cast<float4*>(out + (size_t)B * 72 + (size_t)b0 * 32);
#pragma unroll
            for (int i = 0; i < 8; ++i)
                ko[i] = make_float4(K[4 * i + 0], K[4 * i + 1], K[4 * i + 2], K[4 * i + 3]);
        };

        // ---- counted wait: post-staging vmem = 26 stores exactly, so
        // vmcnt(26) forces everything older (15 loads + 48 gl_lds) complete
        // while all 26 stores may remain in flight. Never 0 in steady state.
        if (full) {
            doStores();
            asm volatile("s_waitcnt vmcnt(26)" ::: "memory");
        } else {
            if (b0 < B) doStores();
            asm volatile("s_waitcnt vmcnt(0)" ::: "memory");
        }

        if (gn >= ngroups) break;
        g = gn;
        zz = zzn; xa = xan; xb = xbn;
    }
}

extern "C" void kernel_launch(void* const* d_in, const int* in_sizes, int n_in,
                              void* d_out, int out_size, void* d_ws, size_t ws_size,
                              hipStream_t stream) {
    const float* x_est = (const float*)d_in[0];
    const float* P_est = (const float*)d_in[1];
    const float* F     = (const float*)d_in[2];
    const float* Q     = (const float*)d_in[3];
    const float* z     = (const float*)d_in[4];
    const float* H     = (const float*)d_in[5];
    const float* R     = (const float*)d_in[6];
    float* out = (float*)d_out;
    int B = in_sizes[0] / 8;
    int ngroups = (B + 63) / 64;
    // 48KB LDS -> 3 blocks/CU; 768 = 3 * 256 CUs.
    int grid = ngroups < 768 ? ngroups : 768;
    kf_kernel<<<grid, 64, 0, stream>>>(x_est, P_est, F, Q, z, H, R, out, B);
}